// Round 2
// baseline (405.838 us; speedup 1.0000x reference)
//
#include <hip/hip_runtime.h>
#include <hip/hip_bf16.h>

// Problem constants (fixed by reference setup)
#define BB 4
#define NN 4096
#define CC 96
#define N1 4097                 // x rows per batch
#define OUTROWS 1025            // 1 CLS + 1024 pooled rows per batch
#define THREADS 512
#define ROWS_PER_BLK 64         // edge rows per block
#define PATCHES_PER_BLK 16      // 64 / 4
#define BLKS_PER_B 64           // 4096 / 64
#define NBLK (BB * BLKS_PER_B)  // 256 blocks -> 1 per CU

__device__ __forceinline__ float fast_sigmoid(float v) {
    // 1/(1+exp(-v)); overflow -> inf -> rcp -> 0 (correct limit)
    return __builtin_amdgcn_rcpf(1.0f + __expf(-v));
}

// Single fused kernel: NO workspace, NO cross-kernel deps. Each block is
// fully self-contained: recomputes t[b,:] for its batch into LDS, computes
// scores for its 64 edge rows, does per-patch argmax + pooled write.
__global__ __launch_bounds__(THREADS) void fused_pool_kernel(
    const float* __restrict__ x, const float* __restrict__ edge,
    const float* __restrict__ theta, float* __restrict__ out)
{
    __shared__ float t_lds[NN];            // 16 KB: t[b,m] for this batch
    __shared__ float partial[8][4];        // [wave][row-in-round]
    __shared__ float s_lds[ROWS_PER_BLK];  // scores for this block's rows

    const int tid     = threadIdx.x;
    const int b       = blockIdx.x >> 6;       // / BLKS_PER_B
    const int blkInB  = blockIdx.x & 63;
    const int rowbase = blkInB * ROWS_PER_BLK;

    const float* xb = x + (size_t)b * N1 * CC;

    // CLS row: out[b,0,:] = x[b,0,:] (one block per batch; every call)
    if (blkInB == 0 && tid < CC)
        out[(size_t)b * OUTROWS * CC + tid] = xb[tid];

    // ---- Phase 1: t[m] = sum_c sigmoid(x[b,m+1,c]) * theta[c] ----
    for (int k = 0; k < NN / THREADS; ++k) {   // 8 rows per thread
        int m = k * THREADS + tid;
        const float* xr = xb + (size_t)(m + 1) * CC;
        float acc = 0.0f;
        #pragma unroll
        for (int c4 = 0; c4 < CC / 4; ++c4) {
            float4 xv = *reinterpret_cast<const float4*>(xr + c4 * 4);
            float4 tw = *reinterpret_cast<const float4*>(theta + c4 * 4);
            acc += fast_sigmoid(xv.x) * tw.x;
            acc += fast_sigmoid(xv.y) * tw.y;
            acc += fast_sigmoid(xv.z) * tw.z;
            acc += fast_sigmoid(xv.w) * tw.w;
        }
        t_lds[m] = acc;
    }
    __syncthreads();

    // ---- Phase 2: scores[n] = sum_m sigmoid(edge[b,n,m]) * t[m] ----
    // Two independent 256-thread groups, each replicating the exact
    // per-thread partition + reduction tree of the validated kernel:
    // thread gtid sums m = {it*1024 + gtid*4 + 0..3}, it = 0..3.
    const int grp      = tid >> 8;      // 0 or 1
    const int gtid     = tid & 255;
    const int gwave    = gtid >> 6;
    const int glane    = gtid & 63;
    const int growbase = rowbase + grp * 32;
    const float* eb = edge + ((size_t)b * NN + growbase) * NN;

    for (int q = 0; q < 8; ++q) {       // 4 rows per round, 32 rows per group
        float a0 = 0.f, a1 = 0.f, a2 = 0.f, a3 = 0.f;
        const float* e0 = eb + (size_t)(q * 4 + 0) * NN;
        const float* e1 = eb + (size_t)(q * 4 + 1) * NN;
        const float* e2 = eb + (size_t)(q * 4 + 2) * NN;
        const float* e3 = eb + (size_t)(q * 4 + 3) * NN;
        #pragma unroll
        for (int it = 0; it < 4; ++it) {
            int idx = it * 1024 + gtid * 4;
            float4 tv = *reinterpret_cast<const float4*>(&t_lds[idx]);
            float4 v0 = *reinterpret_cast<const float4*>(e0 + idx);
            float4 v1 = *reinterpret_cast<const float4*>(e1 + idx);
            float4 v2 = *reinterpret_cast<const float4*>(e2 + idx);
            float4 v3 = *reinterpret_cast<const float4*>(e3 + idx);
            a0 += tv.x * fast_sigmoid(v0.x); a0 += tv.y * fast_sigmoid(v0.y);
            a0 += tv.z * fast_sigmoid(v0.z); a0 += tv.w * fast_sigmoid(v0.w);
            a1 += tv.x * fast_sigmoid(v1.x); a1 += tv.y * fast_sigmoid(v1.y);
            a1 += tv.z * fast_sigmoid(v1.z); a1 += tv.w * fast_sigmoid(v1.w);
            a2 += tv.x * fast_sigmoid(v2.x); a2 += tv.y * fast_sigmoid(v2.y);
            a2 += tv.z * fast_sigmoid(v2.z); a2 += tv.w * fast_sigmoid(v2.w);
            a3 += tv.x * fast_sigmoid(v3.x); a3 += tv.y * fast_sigmoid(v3.y);
            a3 += tv.z * fast_sigmoid(v3.z); a3 += tv.w * fast_sigmoid(v3.w);
        }
        #pragma unroll
        for (int off = 32; off > 0; off >>= 1) {
            a0 += __shfl_down(a0, off, 64);
            a1 += __shfl_down(a1, off, 64);
            a2 += __shfl_down(a2, off, 64);
            a3 += __shfl_down(a3, off, 64);
        }
        if (glane == 0) {
            int w = grp * 4 + gwave;
            partial[w][0] = a0; partial[w][1] = a1;
            partial[w][2] = a2; partial[w][3] = a3;
        }
        __syncthreads();
        if (gtid < 4) {
            int r = gtid;
            int w0 = grp * 4;
            s_lds[grp * 32 + q * 4 + r] =
                partial[w0 + 0][r] + partial[w0 + 1][r] +
                partial[w0 + 2][r] + partial[w0 + 3][r];
        }
        __syncthreads();
    }

    // ---- Phase 3: per-patch argmax-of-4 (strict >, first index on ties,
    // matching jax.lax.top_k) + pooled write out[b, 1+p, :] = (v+1)*node ----
    // Reference quirk: top_k idx is patch-local and indexes nodes[b, 0..3, :].
    const int wave = tid >> 6;
    const int lane = tid & 63;
    for (int pp = wave; pp < PATCHES_PER_BLK; pp += 8) {
        float s0 = s_lds[pp * 4 + 0], s1 = s_lds[pp * 4 + 1];
        float s2 = s_lds[pp * 4 + 2], s3 = s_lds[pp * 4 + 3];
        float best = s0; int bi = 0;
        if (s1 > best) { best = s1; bi = 1; }
        if (s2 > best) { best = s2; bi = 2; }
        if (s3 > best) { best = s3; bi = 3; }
        const float* g = xb + (size_t)(bi + 1) * CC;
        float scale = best + 1.0f;
        float* orow = out + ((size_t)b * OUTROWS + 1 +
                             blkInB * PATCHES_PER_BLK + pp) * CC;
        orow[lane] = scale * g[lane];
        if (lane < CC - 64) orow[lane + 64] = scale * g[lane + 64];
    }
}

extern "C" void kernel_launch(void* const* d_in, const int* in_sizes, int n_in,
                              void* d_out, int out_size, void* d_ws, size_t ws_size,
                              hipStream_t stream) {
    const float* x     = (const float*)d_in[0];   // (4, 4097, 96)
    const float* edge  = (const float*)d_in[1];   // (4, 4096, 4096)
    const float* theta = (const float*)d_in[2];   // (1, 96)
    float* out = (float*)d_out;                   // (4, 1025, 96)

    // Single self-contained kernel; d_ws intentionally unused.
    fused_pool_kernel<<<NBLK, THREADS, 0, stream>>>(x, edge, theta, out);
}